// Round 1
// baseline (2649.113 us; speedup 1.0000x reference)
//
#include <hip/hip_runtime.h>
#include <hip/hip_bf16.h>

#define DD 128

// Y[n][m] = act( sum_k X[n][k]*W[k][m] + bias[m] ), K=M=128, fp32.
// 128-row x 128-col tile per block, 256 threads, 8x8 microtile/thread.
__global__ __launch_bounds__(256) void gemm_rk128(
    const float* __restrict__ X, const float* __restrict__ W,
    const float* __restrict__ bias, float* __restrict__ Y,
    int N, int act)
{
    __shared__ float XsT[128][132];  // [k][r], padded
    __shared__ float Ws[128][132];   // [k][c], padded

    const int tid  = threadIdx.x;
    const int row0 = blockIdx.x * 128;

    // ---- stage X tile (transposed) and W into LDS ----
    #pragma unroll
    for (int i = 0; i < 16; ++i) {
        int f  = tid + 256 * i;      // float4 index over a 128x32 float4 grid
        int r  = f >> 5;             // 0..127
        int k4 = f & 31;             // 0..31
        int gr = row0 + r;
        float4 xv = make_float4(0.f, 0.f, 0.f, 0.f);
        if (gr < N) xv = *(const float4*)(X + (long)gr * DD + k4 * 4);
        XsT[k4 * 4 + 0][r] = xv.x;
        XsT[k4 * 4 + 1][r] = xv.y;
        XsT[k4 * 4 + 2][r] = xv.z;
        XsT[k4 * 4 + 3][r] = xv.w;
        float4 wv = *(const float4*)(W + (long)f * 4);
        *(float4*)&Ws[r][k4 * 4] = wv;   // r is k index here
    }
    __syncthreads();

    const int rg = (tid >> 4) * 8;   // row group 0..120
    const int cg = (tid & 15) * 8;   // col group 0..120

    float acc[8][8];
    #pragma unroll
    for (int a = 0; a < 8; ++a)
        #pragma unroll
        for (int b = 0; b < 8; ++b) acc[a][b] = 0.f;

    #pragma unroll 4
    for (int k = 0; k < 128; ++k) {
        float4 xa = *(const float4*)&XsT[k][rg];
        float4 xb = *(const float4*)&XsT[k][rg + 4];
        float4 wa = *(const float4*)&Ws[k][cg];
        float4 wb = *(const float4*)&Ws[k][cg + 4];
        float xr[8] = {xa.x, xa.y, xa.z, xa.w, xb.x, xb.y, xb.z, xb.w};
        float wc[8] = {wa.x, wa.y, wa.z, wa.w, wb.x, wb.y, wb.z, wb.w};
        #pragma unroll
        for (int a = 0; a < 8; ++a)
            #pragma unroll
            for (int b = 0; b < 8; ++b)
                acc[a][b] = fmaf(xr[a], wc[b], acc[a][b]);
    }

    // ---- epilogue: bias + activation + store ----
    float4 b0 = *(const float4*)(bias + cg);
    float4 b1 = *(const float4*)(bias + cg + 4);
    float bb[8] = {b0.x, b0.y, b0.z, b0.w, b1.x, b1.y, b1.z, b1.w};
    #pragma unroll
    for (int a = 0; a < 8; ++a) {
        int row = row0 + rg + a;
        if (row >= N) break;
        float o[8];
        #pragma unroll
        for (int b = 0; b < 8; ++b) {
            float v = acc[a][b] + bb[b];
            o[b] = act ? fmaxf(v, 0.f) : v;
        }
        *(float4*)(Y + (long)row * DD + cg)     = make_float4(o[0], o[1], o[2], o[3]);
        *(float4*)(Y + (long)row * DD + cg + 4) = make_float4(o[4], o[5], o[6], o[7]);
    }
}

// Per-edge: eta = sigmoid(k[dst]+q[src]+ea@We+be); atomicAdd(agg[dst], eta*v[src]).
// 1 wave per edge, lane handles cols {lane, lane+64}.
__global__ __launch_bounds__(256) void edge_kernel(
    const int* __restrict__ ei, const float* __restrict__ ea,
    const float* __restrict__ We, const float* __restrict__ be,
    const float* __restrict__ K, const float* __restrict__ Q,
    const float* __restrict__ V, float* __restrict__ agg, int E)
{
    const int wave = threadIdx.x >> 6;
    const int lane = threadIdx.x & 63;
    const long e = (long)blockIdx.x * 4 + wave;
    if (e >= E) return;

    const int s = ei[e];
    const int d = ei[(long)E + e];
    const float* eap = ea + e * 21;

    float et0 = be[lane];
    float et1 = be[lane + 64];
    #pragma unroll
    for (int j = 0; j < 21; ++j) {
        float a = eap[j];                  // uniform per wave -> broadcast
        et0 = fmaf(a, We[j * DD + lane],      et0);
        et1 = fmaf(a, We[j * DD + lane + 64], et1);
    }

    const float* kd = K + (long)d * DD;
    const float* qs = Q + (long)s * DD;
    const float* vs = V + (long)s * DD;

    float z0 = kd[lane]      + qs[lane]      + et0;
    float z1 = kd[lane + 64] + qs[lane + 64] + et1;
    float eta0 = 1.f / (1.f + __expf(-z0));
    float eta1 = 1.f / (1.f + __expf(-z1));

    atomicAdd(&agg[(long)d * DD + lane],      eta0 * vs[lane]);
    atomicAdd(&agg[(long)d * DD + lane + 64], eta1 * vs[lane + 64]);
}

__global__ void relu_inplace(float* __restrict__ x, long n4)
{
    long i = (long)blockIdx.x * blockDim.x + threadIdx.x;
    for (; i < n4; i += (long)gridDim.x * blockDim.x) {
        float4 v = ((float4*)x)[i];
        v.x = fmaxf(v.x, 0.f); v.y = fmaxf(v.y, 0.f);
        v.z = fmaxf(v.z, 0.f); v.w = fmaxf(v.w, 0.f);
        ((float4*)x)[i] = v;
    }
}

// column sums of x[N][128] into gsum[128] (gsum pre-zeroed)
__global__ void colsum_kernel(const float* __restrict__ x, float* __restrict__ gsum, int N)
{
    const int c = threadIdx.x;   // 128 threads
    float acc = 0.f;
    for (int r = blockIdx.x; r < N; r += gridDim.x)
        acc += x[(long)r * DD + c];
    atomicAdd(&gsum[c], acc);
}

// cvec[m] = h1b[m] + sum_k (gsum[k]/N) * h1W[(128+k)*128 + m]
__global__ void cvec_kernel(const float* __restrict__ gsum, const float* __restrict__ h1W,
                            const float* __restrict__ h1b, float* __restrict__ cvec, float invN)
{
    const int m = threadIdx.x;   // 128 threads
    float acc = h1b[m];
    for (int k = 0; k < 128; ++k)
        acc = fmaf(gsum[k] * invN, h1W[(long)(128 + k) * DD + m], acc);
    cvec[m] = acc;
}

// out[n] = x[n] . w + b   (1 wave per node)
__global__ __launch_bounds__(256) void head3_kernel(
    const float* __restrict__ x, const float* __restrict__ w,
    const float* __restrict__ b, float* __restrict__ out, int N)
{
    const int wave = threadIdx.x >> 6;
    const int lane = threadIdx.x & 63;
    const long n = (long)blockIdx.x * 4 + wave;
    if (n >= N) return;
    float acc = x[n * DD + lane] * w[lane] + x[n * DD + 64 + lane] * w[64 + lane];
    #pragma unroll
    for (int off = 32; off > 0; off >>= 1)
        acc += __shfl_down(acc, off, 64);
    if (lane == 0) out[n] = acc + b[0];
}

extern "C" void kernel_launch(void* const* d_in, const int* in_sizes, int n_in,
                              void* d_out, int out_size, void* d_ws, size_t ws_size,
                              hipStream_t stream)
{
    const float* G    = (const float*)d_in[0];
    const int*   ei   = (const int*)  d_in[1];
    const float* ea   = (const float*)d_in[2];
    const float* embW = (const float*)d_in[3];
    const float* embb = (const float*)d_in[4];
    const float* keyW = (const float*)d_in[5];
    const float* keyb = (const float*)d_in[6];
    const float* qryW = (const float*)d_in[7];
    const float* qryb = (const float*)d_in[8];
    const float* valW = (const float*)d_in[9];
    const float* valb = (const float*)d_in[10];
    const float* skpW = (const float*)d_in[11];
    const float* skpb = (const float*)d_in[12];
    const float* edgW = (const float*)d_in[13];
    const float* edgb = (const float*)d_in[14];
    const float* g1W  = (const float*)d_in[15];
    const float* g1b  = (const float*)d_in[16];
    const float* g2W  = (const float*)d_in[17];
    const float* g2b  = (const float*)d_in[18];
    const float* h1W  = (const float*)d_in[19];
    const float* h1b  = (const float*)d_in[20];
    const float* h2W  = (const float*)d_in[21];
    const float* h2b  = (const float*)d_in[22];
    const float* h3W  = (const float*)d_in[23];
    const float* h3b  = (const float*)d_in[24];

    const int N = in_sizes[0] / DD;    // 100000
    const int E = in_sizes[2] / 21;    // 1000000

    const size_t S = (size_t)N * DD;
    float* buf0 = (float*)d_ws;
    float* buf1 = buf0 + S;
    float* buf2 = buf1 + S;
    float* buf3 = buf2 + S;
    float* buf4 = buf3 + S;
    float* gsum = buf4 + S;       // 128
    float* cvec = gsum + DD;      // 128

    const int gemmGrid = (N + 127) / 128;
    const int edgeGrid = (E + 3) / 4;
    const int waveGrid = (N + 3) / 4;

    // embedding MLP: G -> buf0 -> buf1 -> buf0
    gemm_rk128<<<gemmGrid, 256, 0, stream>>>(G,    embW + 0*DD*DD, embb + 0*DD, buf0, N, 1);
    gemm_rk128<<<gemmGrid, 256, 0, stream>>>(buf0, embW + 1*DD*DD, embb + 1*DD, buf1, N, 1);
    gemm_rk128<<<gemmGrid, 256, 0, stream>>>(buf1, embW + 2*DD*DD, embb + 2*DD, buf0, N, 1);

    // conv layer 0: x = buf0, agg -> buf4
    gemm_rk128<<<gemmGrid, 256, 0, stream>>>(buf0, keyW + 0, keyb + 0, buf1, N, 0);   // k
    gemm_rk128<<<gemmGrid, 256, 0, stream>>>(buf0, qryW + 0, qryb + 0, buf2, N, 0);   // q
    gemm_rk128<<<gemmGrid, 256, 0, stream>>>(buf0, valW + 0, valb + 0, buf3, N, 0);   // v
    gemm_rk128<<<gemmGrid, 256, 0, stream>>>(buf0, skpW + 0, skpb + 0, buf4, N, 0);   // skip -> agg
    edge_kernel<<<edgeGrid, 256, 0, stream>>>(ei, ea, edgW + 0, edgb + 0,
                                              buf1, buf2, buf3, buf4, E);
    relu_inplace<<<2048, 256, 0, stream>>>(buf4, (long)(S / 4));

    // conv layer 1: x = buf4, agg -> buf0
    gemm_rk128<<<gemmGrid, 256, 0, stream>>>(buf4, keyW + DD*DD, keyb + DD, buf1, N, 0);
    gemm_rk128<<<gemmGrid, 256, 0, stream>>>(buf4, qryW + DD*DD, qryb + DD, buf2, N, 0);
    gemm_rk128<<<gemmGrid, 256, 0, stream>>>(buf4, valW + DD*DD, valb + DD, buf3, N, 0);
    gemm_rk128<<<gemmGrid, 256, 0, stream>>>(buf4, skpW + DD*DD, skpb + DD, buf0, N, 0);
    edge_kernel<<<edgeGrid, 256, 0, stream>>>(ei, ea, edgW + 21*DD, edgb + DD,
                                              buf1, buf2, buf3, buf0, E);
    relu_inplace<<<2048, 256, 0, stream>>>(buf0, (long)(S / 4));

    // graph linears: buf0 -> buf1 (relu) -> buf2 (none)
    gemm_rk128<<<gemmGrid, 256, 0, stream>>>(buf0, g1W, g1b, buf1, N, 1);
    gemm_rk128<<<gemmGrid, 256, 0, stream>>>(buf1, g2W, g2b, buf2, N, 0);

    // graph mean -> cvec = h1b + (gmean @ h1W[D:])
    hipMemsetAsync(gsum, 0, DD * sizeof(float), stream);
    colsum_kernel<<<256, DD, 0, stream>>>(buf2, gsum, N);
    cvec_kernel<<<1, DD, 0, stream>>>(gsum, h1W, h1b, cvec, 1.0f / (float)N);

    // head: h1 (x @ h1W[:D] + cvec, relu) -> buf3 ; h2 -> buf1 ; h3 -> out
    gemm_rk128<<<gemmGrid, 256, 0, stream>>>(buf2, h1W, cvec, buf3, N, 1);
    gemm_rk128<<<gemmGrid, 256, 0, stream>>>(buf3, h2W, h2b, buf1, N, 1);
    head3_kernel<<<waveGrid, 256, 0, stream>>>(buf1, h3W, h3b, (float*)d_out, N);
}

// Round 2
// 2467.776 us; speedup vs baseline: 1.0735x; 1.0735x over previous
//
#include <hip/hip_runtime.h>
#include <hip/hip_bf16.h>

#define DD 128

// Y[n][m] = act( sum_k X[n][k]*W[k][m] + bias[m] ), K=M=128, fp32.
// 128-row x 128-col tile per block, 256 threads, 8x8 microtile/thread.
__global__ __launch_bounds__(256) void gemm_rk128(
    const float* __restrict__ X, const float* __restrict__ W,
    const float* __restrict__ bias, float* __restrict__ Y,
    int N, int act)
{
    __shared__ float XsT[128][132];  // [k][r], padded
    __shared__ float Ws[128][132];   // [k][c], padded

    const int tid  = threadIdx.x;
    const int row0 = blockIdx.x * 128;

    #pragma unroll
    for (int i = 0; i < 16; ++i) {
        int f  = tid + 256 * i;
        int r  = f >> 5;
        int k4 = f & 31;
        int gr = row0 + r;
        float4 xv = make_float4(0.f, 0.f, 0.f, 0.f);
        if (gr < N) xv = *(const float4*)(X + (long)gr * DD + k4 * 4);
        XsT[k4 * 4 + 0][r] = xv.x;
        XsT[k4 * 4 + 1][r] = xv.y;
        XsT[k4 * 4 + 2][r] = xv.z;
        XsT[k4 * 4 + 3][r] = xv.w;
        float4 wv = *(const float4*)(W + (long)f * 4);
        *(float4*)&Ws[r][k4 * 4] = wv;
    }
    __syncthreads();

    const int rg = (tid >> 4) * 8;
    const int cg = (tid & 15) * 8;

    float acc[8][8];
    #pragma unroll
    for (int a = 0; a < 8; ++a)
        #pragma unroll
        for (int b = 0; b < 8; ++b) acc[a][b] = 0.f;

    #pragma unroll 4
    for (int k = 0; k < 128; ++k) {
        float4 xa = *(const float4*)&XsT[k][rg];
        float4 xb = *(const float4*)&XsT[k][rg + 4];
        float4 wa = *(const float4*)&Ws[k][cg];
        float4 wb = *(const float4*)&Ws[k][cg + 4];
        float xr[8] = {xa.x, xa.y, xa.z, xa.w, xb.x, xb.y, xb.z, xb.w};
        float wc[8] = {wa.x, wa.y, wa.z, wa.w, wb.x, wb.y, wb.z, wb.w};
        #pragma unroll
        for (int a = 0; a < 8; ++a)
            #pragma unroll
            for (int b = 0; b < 8; ++b)
                acc[a][b] = fmaf(xr[a], wc[b], acc[a][b]);
    }

    float4 b0 = *(const float4*)(bias + cg);
    float4 b1 = *(const float4*)(bias + cg + 4);
    float bb[8] = {b0.x, b0.y, b0.z, b0.w, b1.x, b1.y, b1.z, b1.w};
    #pragma unroll
    for (int a = 0; a < 8; ++a) {
        int row = row0 + rg + a;
        if (row >= N) break;
        float o[8];
        #pragma unroll
        for (int b = 0; b < 8; ++b) {
            float v = acc[a][b] + bb[b];
            o[b] = act ? fmaxf(v, 0.f) : v;
        }
        *(float4*)(Y + (long)row * DD + cg)     = make_float4(o[0], o[1], o[2], o[3]);
        *(float4*)(Y + (long)row * DD + cg + 4) = make_float4(o[4], o[5], o[6], o[7]);
    }
}

// ---------------- CSR build ----------------
__global__ void hist_kernel(const int* __restrict__ dstA, int* __restrict__ hist, int E)
{
    for (int e = blockIdx.x * blockDim.x + threadIdx.x; e < E;
         e += gridDim.x * blockDim.x)
        atomicAdd(&hist[dstA[e]], 1);
}

// block of 256 threads scans 1024 elements; exclusive within block + block total
__global__ __launch_bounds__(256) void scan1_kernel(
    const int* __restrict__ in, int n_in,
    int* __restrict__ out, int* __restrict__ bsum, int n)
{
    __shared__ int wtot[4];
    const int t = threadIdx.x, lane = t & 63, wv = t >> 6;
    const int base = blockIdx.x * 1024 + t * 4;
    int v[4]; int sum = 0;
    #pragma unroll
    for (int j = 0; j < 4; ++j) {
        int idx = base + j;
        v[j] = (idx < n_in) ? in[idx] : 0;
        sum += v[j];
    }
    int incl = sum;
    #pragma unroll
    for (int d = 1; d < 64; d <<= 1) {
        int y = __shfl_up(incl, d, 64);
        if (lane >= d) incl += y;
    }
    if (lane == 63) wtot[wv] = incl;
    __syncthreads();
    int woff = 0;
    for (int w = 0; w < wv; ++w) woff += wtot[w];
    int run = woff + incl - sum;   // exclusive prefix for this thread's chunk
    #pragma unroll
    for (int j = 0; j < 4; ++j) {
        int idx = base + j;
        if (idx < n) out[idx] = run;
        run += v[j];
    }
    if (t == 0)
        bsum[blockIdx.x] = wtot[0] + wtot[1] + wtot[2] + wtot[3];
}

__global__ void scan2_kernel(int* __restrict__ bsum, int nb)
{
    if (blockIdx.x == 0 && threadIdx.x == 0) {
        int run = 0;
        for (int i = 0; i < nb; ++i) { int t = bsum[i]; bsum[i] = run; run += t; }
    }
}

__global__ __launch_bounds__(256) void scan3_kernel(
    int* __restrict__ out, const int* __restrict__ bsum,
    int* __restrict__ cursor, int n, int n_nodes)
{
    const int base = blockIdx.x * 1024 + threadIdx.x * 4;
    const int add = bsum[blockIdx.x];
    #pragma unroll
    for (int j = 0; j < 4; ++j) {
        int idx = base + j;
        if (idx < n) {
            int vv = out[idx] + add;
            out[idx] = vv;
            if (idx < n_nodes) cursor[idx] = vv;
        }
    }
}

__global__ void scatter_kernel(const int* __restrict__ srcA, const int* __restrict__ dstA,
                               int* __restrict__ cursor, int* __restrict__ perm,
                               int* __restrict__ srcp, int E)
{
    for (int e = blockIdx.x * blockDim.x + threadIdx.x; e < E;
         e += gridDim.x * blockDim.x) {
        int d = dstA[e];
        int pos = atomicAdd(&cursor[d], 1);
        perm[pos] = e;
        srcp[pos] = srcA[e];
    }
}

__global__ void permute_ea_kernel(const float* __restrict__ ea, const int* __restrict__ perm,
                                  float* __restrict__ eap, long E)
{
    const long total = E * 21;
    for (long t = (long)blockIdx.x * blockDim.x + threadIdx.x; t < total;
         t += (long)gridDim.x * blockDim.x) {
        long i = t / 21; int j = (int)(t - i * 21);
        eap[t] = ea[(long)perm[i] * 21 + j];
    }
}

// ---------------- edge aggregation: one wave per dst node ----------------
// out[d] = relu( Sk[d] + sum_{edges i into d} sigmoid(K[d]+Q[s]+ea_i@We+be) * V[s] )
__global__ __launch_bounds__(256) void edge_agg_kernel(
    const int* __restrict__ row_ptr, const int* __restrict__ srcp,
    const float* __restrict__ eadat, const int* __restrict__ perm, int indirect,
    const float* __restrict__ We, const float* __restrict__ be,
    const float* __restrict__ K, const float* __restrict__ Q,
    const float* __restrict__ V, const float* __restrict__ Sk,
    float* __restrict__ Xout, int N)
{
    const int wv = threadIdx.x >> 6, lane = threadIdx.x & 63;
    const int d = blockIdx.x * 4 + wv;
    if (d >= N) return;

    float w0[21], w1[21];
    #pragma unroll
    for (int j = 0; j < 21; ++j) {
        w0[j] = We[j * DD + lane];
        w1[j] = We[j * DD + 64 + lane];
    }
    const float b0 = be[lane], b1 = be[lane + 64];
    const float kd0 = K[(long)d * DD + lane];
    const float kd1 = K[(long)d * DD + 64 + lane];

    float acc0 = 0.f, acc1 = 0.f;
    const int i0 = row_ptr[d], i1 = row_ptr[d + 1];
    for (int i = i0; i < i1; ++i) {
        const float* eap = indirect ? (eadat + (long)perm[i] * 21)
                                    : (eadat + (long)i * 21);
        const int s = srcp[i];
        float et0 = b0, et1 = b1;
        #pragma unroll
        for (int j = 0; j < 21; ++j) {
            float a = eap[j];
            et0 = fmaf(a, w0[j], et0);
            et1 = fmaf(a, w1[j], et1);
        }
        const float* qs = Q + (long)s * DD;
        const float* vs = V + (long)s * DD;
        float z0 = kd0 + qs[lane]      + et0;
        float z1 = kd1 + qs[lane + 64] + et1;
        float eta0 = 1.f / (1.f + __expf(-z0));
        float eta1 = 1.f / (1.f + __expf(-z1));
        acc0 = fmaf(eta0, vs[lane],      acc0);
        acc1 = fmaf(eta1, vs[lane + 64], acc1);
    }
    float o0 = acc0 + Sk[(long)d * DD + lane];
    float o1 = acc1 + Sk[(long)d * DD + 64 + lane];
    Xout[(long)d * DD + lane]      = fmaxf(o0, 0.f);
    Xout[(long)d * DD + 64 + lane] = fmaxf(o1, 0.f);
}

// column sums of x[N][128] into gsum[128] (gsum pre-zeroed)
__global__ void colsum_kernel(const float* __restrict__ x, float* __restrict__ gsum, int N)
{
    const int c = threadIdx.x;
    float acc = 0.f;
    for (int r = blockIdx.x; r < N; r += gridDim.x)
        acc += x[(long)r * DD + c];
    atomicAdd(&gsum[c], acc);
}

__global__ void cvec_kernel(const float* __restrict__ gsum, const float* __restrict__ h1W,
                            const float* __restrict__ h1b, float* __restrict__ cvec, float invN)
{
    const int m = threadIdx.x;
    float acc = h1b[m];
    for (int k = 0; k < 128; ++k)
        acc = fmaf(gsum[k] * invN, h1W[(long)(128 + k) * DD + m], acc);
    cvec[m] = acc;
}

__global__ __launch_bounds__(256) void head3_kernel(
    const float* __restrict__ x, const float* __restrict__ w,
    const float* __restrict__ b, float* __restrict__ out, int N)
{
    const int wave = threadIdx.x >> 6;
    const int lane = threadIdx.x & 63;
    const long n = (long)blockIdx.x * 4 + wave;
    if (n >= N) return;
    float acc = x[n * DD + lane] * w[lane] + x[n * DD + 64 + lane] * w[64 + lane];
    #pragma unroll
    for (int off = 32; off > 0; off >>= 1)
        acc += __shfl_down(acc, off, 64);
    if (lane == 0) out[n] = acc + b[0];
}

extern "C" void kernel_launch(void* const* d_in, const int* in_sizes, int n_in,
                              void* d_out, int out_size, void* d_ws, size_t ws_size,
                              hipStream_t stream)
{
    const float* G    = (const float*)d_in[0];
    const int*   ei   = (const int*)  d_in[1];
    const float* ea   = (const float*)d_in[2];
    const float* embW = (const float*)d_in[3];
    const float* embb = (const float*)d_in[4];
    const float* keyW = (const float*)d_in[5];
    const float* keyb = (const float*)d_in[6];
    const float* qryW = (const float*)d_in[7];
    const float* qryb = (const float*)d_in[8];
    const float* valW = (const float*)d_in[9];
    const float* valb = (const float*)d_in[10];
    const float* skpW = (const float*)d_in[11];
    const float* skpb = (const float*)d_in[12];
    const float* edgW = (const float*)d_in[13];
    const float* edgb = (const float*)d_in[14];
    const float* g1W  = (const float*)d_in[15];
    const float* g1b  = (const float*)d_in[16];
    const float* g2W  = (const float*)d_in[17];
    const float* g2b  = (const float*)d_in[18];
    const float* h1W  = (const float*)d_in[19];
    const float* h1b  = (const float*)d_in[20];
    const float* h2W  = (const float*)d_in[21];
    const float* h2b  = (const float*)d_in[22];
    const float* h3W  = (const float*)d_in[23];
    const float* h3b  = (const float*)d_in[24];

    const int N = in_sizes[0] / DD;    // 100000
    const int E = in_sizes[2] / 21;    // 1000000
    const int* srcA = ei;
    const int* dstA = ei + E;

    const size_t S = (size_t)N * DD;
    float* bx = (float*)d_ws;      // activations
    float* bK = bx + S;
    float* bQ = bK + S;
    float* bV = bQ + S;
    float* bS = bV + S;
    float* gsum = bS + S;          // 128
    float* cvec = gsum + DD;       // 128
    int* hist = (int*)(cvec + DD); // N
    int* row  = hist + N;          // N+1
    int* cur  = row + N + 1;       // N
    int* bsum = cur + N;           // 128
    int* perm = bsum + 128;        // E
    int* srcp = perm + E;          // E
    float* ea_perm = (float*)(srcp + E);   // E*21 floats (optional)

    const size_t base_bytes = (size_t)((char*)ea_perm - (char*)d_ws);
    const bool room = ws_size >= base_bytes + (size_t)E * 21 * sizeof(float);

    const int gemmGrid = (N + 127) / 128;
    const int aggGrid  = (N + 3) / 4;
    const int waveGrid = (N + 3) / 4;
    const int nScan = N + 1;
    const int nb = (nScan + 1023) / 1024;

    // ---- CSR build (once, reused by both conv layers) ----
    hipMemsetAsync(hist, 0, (size_t)N * sizeof(int), stream);
    hist_kernel<<<1024, 256, 0, stream>>>(dstA, hist, E);
    scan1_kernel<<<nb, 256, 0, stream>>>(hist, N, row, bsum, nScan);
    scan2_kernel<<<1, 64, 0, stream>>>(bsum, nb);
    scan3_kernel<<<nb, 256, 0, stream>>>(row, bsum, cur, nScan, N);
    scatter_kernel<<<1024, 256, 0, stream>>>(srcA, dstA, cur, perm, srcp, E);
    if (room)
        permute_ea_kernel<<<2048, 256, 0, stream>>>(ea, perm, ea_perm, (long)E);
    const float* eadat = room ? ea_perm : ea;
    const int indirect = room ? 0 : 1;

    // ---- embedding MLP: G -> bK -> bQ -> bx ----
    gemm_rk128<<<gemmGrid, 256, 0, stream>>>(G,  embW + 0*DD*DD, embb + 0*DD, bK, N, 1);
    gemm_rk128<<<gemmGrid, 256, 0, stream>>>(bK, embW + 1*DD*DD, embb + 1*DD, bQ, N, 1);
    gemm_rk128<<<gemmGrid, 256, 0, stream>>>(bQ, embW + 2*DD*DD, embb + 2*DD, bx, N, 1);

    // ---- conv layer 0 ----
    gemm_rk128<<<gemmGrid, 256, 0, stream>>>(bx, keyW + 0, keyb + 0, bK, N, 0);
    gemm_rk128<<<gemmGrid, 256, 0, stream>>>(bx, qryW + 0, qryb + 0, bQ, N, 0);
    gemm_rk128<<<gemmGrid, 256, 0, stream>>>(bx, valW + 0, valb + 0, bV, N, 0);
    gemm_rk128<<<gemmGrid, 256, 0, stream>>>(bx, skpW + 0, skpb + 0, bS, N, 0);
    edge_agg_kernel<<<aggGrid, 256, 0, stream>>>(row, srcp, eadat, perm, indirect,
                                                 edgW + 0, edgb + 0,
                                                 bK, bQ, bV, bS, bx, N);

    // ---- conv layer 1 ----
    gemm_rk128<<<gemmGrid, 256, 0, stream>>>(bx, keyW + DD*DD, keyb + DD, bK, N, 0);
    gemm_rk128<<<gemmGrid, 256, 0, stream>>>(bx, qryW + DD*DD, qryb + DD, bQ, N, 0);
    gemm_rk128<<<gemmGrid, 256, 0, stream>>>(bx, valW + DD*DD, valb + DD, bV, N, 0);
    gemm_rk128<<<gemmGrid, 256, 0, stream>>>(bx, skpW + DD*DD, skpb + DD, bS, N, 0);
    edge_agg_kernel<<<aggGrid, 256, 0, stream>>>(row, srcp, eadat, perm, indirect,
                                                 edgW + 21*DD, edgb + DD,
                                                 bK, bQ, bV, bS, bx, N);

    // ---- graph linears: bx -> bK (relu) -> bQ ----
    gemm_rk128<<<gemmGrid, 256, 0, stream>>>(bx, g1W, g1b, bK, N, 1);
    gemm_rk128<<<gemmGrid, 256, 0, stream>>>(bK, g2W, g2b, bQ, N, 0);

    // ---- graph mean -> cvec ----
    hipMemsetAsync(gsum, 0, DD * sizeof(float), stream);
    colsum_kernel<<<256, DD, 0, stream>>>(bQ, gsum, N);
    cvec_kernel<<<1, DD, 0, stream>>>(gsum, h1W, h1b, cvec, 1.0f / (float)N);

    // ---- head ----
    gemm_rk128<<<gemmGrid, 256, 0, stream>>>(bQ, h1W, cvec, bV, N, 1);
    gemm_rk128<<<gemmGrid, 256, 0, stream>>>(bV, h2W, h2b, bK, N, 1);
    head3_kernel<<<waveGrid, 256, 0, stream>>>(bK, h3W, h3b, (float*)d_out, N);
}

// Round 3
// 1902.605 us; speedup vs baseline: 1.3924x; 1.2971x over previous
//
#include <hip/hip_runtime.h>
#include <hip/hip_bf16.h>

#define DD 128

typedef __attribute__((ext_vector_type(8))) short bf16x8;
typedef __attribute__((ext_vector_type(4))) float f32x4;

// split 8 fp32 -> packed bf16 hi (truncate) and lo (truncate of residual)
__device__ __forceinline__ void cvt8(const float4 a0, const float4 a1,
                                     bf16x8& hi, bf16x8& lo)
{
    float af[8] = {a0.x, a0.y, a0.z, a0.w, a1.x, a1.y, a1.z, a1.w};
    union { unsigned int u[4]; bf16x8 v; } H, L;
    #pragma unroll
    for (int i = 0; i < 4; ++i) {
        unsigned int b0 = __float_as_uint(af[2*i]);
        unsigned int b1 = __float_as_uint(af[2*i+1]);
        unsigned int h0 = b0 & 0xFFFF0000u;
        unsigned int h1 = b1 & 0xFFFF0000u;
        H.u[i] = (h0 >> 16) | h1;
        float r0 = af[2*i]   - __uint_as_float(h0);
        float r1 = af[2*i+1] - __uint_as_float(h1);
        L.u[i] = (__float_as_uint(r0) >> 16) | (__float_as_uint(r1) & 0xFFFF0000u);
    }
    hi = H.v; lo = L.v;
}

// Y[n][colW+...] = act( X[n][:] @ Wunit[cb] + bias[cb*128+...] )
// X: [N][128] fp32. Wt: per col-block 128x128 unit: hi[128][128] then lo (bf16, [m][k]).
// grid = (ceil(N/128), nColBlocks). 256 threads, 4 waves, wave tile 64x64, no LDS.
__global__ __launch_bounds__(256) void gemm_mfma(
    const float* __restrict__ X, const unsigned short* __restrict__ Wt,
    const float* __restrict__ bias, float* __restrict__ Y,
    int N, int ldY, int act)
{
    const int lane = threadIdx.x & 63;
    const int wid  = threadIdx.x >> 6;
    const int wr = wid >> 1, wc = wid & 1;
    const int row0 = blockIdx.x * 128 + wr * 64;
    const int cb   = blockIdx.y;
    const unsigned short* WtH = Wt + (size_t)cb * 32768;
    const unsigned short* WtL = WtH + 16384;

    const int l15 = lane & 15;
    const int kg  = (lane >> 4) * 8;

    f32x4 acc[4][4] = {};

    int arow[4];
    #pragma unroll
    for (int mi = 0; mi < 4; ++mi) {
        int r = row0 + mi * 16 + l15;
        arow[mi] = r < N ? r : N - 1;
    }

    #pragma unroll
    for (int kc = 0; kc < 4; ++kc) {
        const int kb = kc * 32 + kg;
        bf16x8 ah[4], al[4], bh[4], bl[4];
        #pragma unroll
        for (int mi = 0; mi < 4; ++mi) {
            const float* p = X + (size_t)arow[mi] * DD + kb;
            float4 a0 = *(const float4*)p;
            float4 a1 = *(const float4*)(p + 4);
            cvt8(a0, a1, ah[mi], al[mi]);
        }
        #pragma unroll
        for (int ni = 0; ni < 4; ++ni) {
            int m = wc * 64 + ni * 16 + l15;
            bh[ni] = *(const bf16x8*)(WtH + (size_t)m * DD + kb);
            bl[ni] = *(const bf16x8*)(WtL + (size_t)m * DD + kb);
        }
        #pragma unroll
        for (int mi = 0; mi < 4; ++mi)
            #pragma unroll
            for (int ni = 0; ni < 4; ++ni) {
                acc[mi][ni] = __builtin_amdgcn_mfma_f32_16x16x32_bf16(ah[mi], bh[ni], acc[mi][ni], 0, 0, 0);
                acc[mi][ni] = __builtin_amdgcn_mfma_f32_16x16x32_bf16(ah[mi], bl[ni], acc[mi][ni], 0, 0, 0);
                acc[mi][ni] = __builtin_amdgcn_mfma_f32_16x16x32_bf16(al[mi], bh[ni], acc[mi][ni], 0, 0, 0);
            }
    }

    const int colW = cb * 128 + wc * 64;
    #pragma unroll
    for (int ni = 0; ni < 4; ++ni) {
        float bv = bias[colW + ni * 16 + l15];
        #pragma unroll
        for (int mi = 0; mi < 4; ++mi) {
            #pragma unroll
            for (int r = 0; r < 4; ++r) {
                int row = row0 + mi * 16 + (lane >> 4) * 4 + r;
                if (row < N) {
                    float v = acc[mi][ni][r] + bv;
                    Y[(size_t)row * ldY + colW + ni * 16 + l15] = act ? fmaxf(v, 0.f) : v;
                }
            }
        }
    }
}

// one-time: transpose+split all 15 [128][128] weight units to bf16 hi/lo [m][k],
// and build the concat bias for the fused kqvs GEMMs.
__global__ __launch_bounds__(256) void prep_weights(
    const float* __restrict__ embW, const float* __restrict__ keyW,
    const float* __restrict__ qryW, const float* __restrict__ valW,
    const float* __restrict__ skpW, const float* __restrict__ g1W,
    const float* __restrict__ g2W, const float* __restrict__ h1W,
    const float* __restrict__ h2W,
    const float* __restrict__ keyb, const float* __restrict__ qryb,
    const float* __restrict__ valb, const float* __restrict__ skpb,
    unsigned short* __restrict__ Wt, float* __restrict__ biasCat)
{
    const int u = blockIdx.x;   // 0..14
    const float* src;
    if (u < 3)       src = embW + (size_t)u * 16384;
    else if (u < 7)  { const float* p[4] = {keyW, qryW, valW, skpW}; src = p[u - 3]; }
    else if (u < 11) { const float* p[4] = {keyW, qryW, valW, skpW}; src = p[u - 7] + 16384; }
    else if (u == 11) src = g1W;
    else if (u == 12) src = g2W;
    else if (u == 13) src = h1W;     // first 128 rows of [256,128]
    else              src = h2W;

    __shared__ float T[128][129];
    const int t = threadIdx.x;
    #pragma unroll
    for (int i = 0; i < 64; ++i) {
        int idx = t + 256 * i;
        T[idx >> 7][idx & 127] = src[idx];
    }
    __syncthreads();

    unsigned short* dH = Wt + (size_t)u * 32768;
    unsigned short* dL = dH + 16384;
    const int m = t >> 1, kbase = (t & 1) * 64;
    for (int j = 0; j < 64; ++j) {
        int k = kbase + j;
        float a = T[k][m];
        unsigned int b = __float_as_uint(a);
        unsigned int h = b & 0xFFFF0000u;
        float r = a - __uint_as_float(h);
        dH[m * 128 + k] = (unsigned short)(h >> 16);
        dL[m * 128 + k] = (unsigned short)(__float_as_uint(r) >> 16);
    }

    if (u == 0) {
        for (int x = t; x < 1024; x += 256) {
            int L = x >> 9, c = x & 511;
            const float* bp = (c < 128) ? keyb : (c < 256) ? qryb : (c < 384) ? valb : skpb;
            biasCat[x] = bp[L * 128 + (c & 127)];
        }
    }
}

// ---------------- CSR build ----------------
__global__ void hist_kernel(const int* __restrict__ dstA, int* __restrict__ hist, int E)
{
    for (int e = blockIdx.x * blockDim.x + threadIdx.x; e < E;
         e += gridDim.x * blockDim.x)
        atomicAdd(&hist[dstA[e]], 1);
}

__global__ __launch_bounds__(256) void scan1_kernel(
    const int* __restrict__ in, int n_in,
    int* __restrict__ out, int* __restrict__ bsum, int n)
{
    __shared__ int wtot[4];
    const int t = threadIdx.x, lane = t & 63, wv = t >> 6;
    const int base = blockIdx.x * 1024 + t * 4;
    int v[4]; int sum = 0;
    #pragma unroll
    for (int j = 0; j < 4; ++j) {
        int idx = base + j;
        v[j] = (idx < n_in) ? in[idx] : 0;
        sum += v[j];
    }
    int incl = sum;
    #pragma unroll
    for (int d = 1; d < 64; d <<= 1) {
        int y = __shfl_up(incl, d, 64);
        if (lane >= d) incl += y;
    }
    if (lane == 63) wtot[wv] = incl;
    __syncthreads();
    int woff = 0;
    for (int w = 0; w < wv; ++w) woff += wtot[w];
    int run = woff + incl - sum;
    #pragma unroll
    for (int j = 0; j < 4; ++j) {
        int idx = base + j;
        if (idx < n) out[idx] = run;
        run += v[j];
    }
    if (t == 0)
        bsum[blockIdx.x] = wtot[0] + wtot[1] + wtot[2] + wtot[3];
}

__global__ void scan2_kernel(int* __restrict__ bsum, int nb)
{
    if (blockIdx.x == 0 && threadIdx.x == 0) {
        int run = 0;
        for (int i = 0; i < nb; ++i) { int t = bsum[i]; bsum[i] = run; run += t; }
    }
}

__global__ __launch_bounds__(256) void scan3_kernel(
    int* __restrict__ out, const int* __restrict__ bsum,
    int* __restrict__ cursor, int n, int n_nodes)
{
    const int base = blockIdx.x * 1024 + threadIdx.x * 4;
    const int add = bsum[blockIdx.x];
    #pragma unroll
    for (int j = 0; j < 4; ++j) {
        int idx = base + j;
        if (idx < n) {
            int vv = out[idx] + add;
            out[idx] = vv;
            if (idx < n_nodes) cursor[idx] = vv;
        }
    }
}

__global__ void scatter_kernel(const int* __restrict__ srcA, const int* __restrict__ dstA,
                               int* __restrict__ cursor, int* __restrict__ perm,
                               int* __restrict__ srcp, int E)
{
    for (int e = blockIdx.x * blockDim.x + threadIdx.x; e < E;
         e += gridDim.x * blockDim.x) {
        int d = dstA[e];
        int pos = atomicAdd(&cursor[d], 1);
        perm[pos] = e;
        srcp[pos] = srcA[e];
    }
}

__global__ void permute_ea_kernel(const float* __restrict__ ea, const int* __restrict__ perm,
                                  float* __restrict__ eap, long E)
{
    const long total = E * 21;
    for (long t = (long)blockIdx.x * blockDim.x + threadIdx.x; t < total;
         t += (long)gridDim.x * blockDim.x) {
        long i = t / 21; int j = (int)(t - i * 21);
        eap[t] = ea[(long)perm[i] * 21 + j];
    }
}

// ---------------- edge aggregation: one wave per dst, 4-edge batched prefetch --------
// fused layout per row: [K | Q | V | Sk] (4 x 128)
__global__ __launch_bounds__(256) void edge_agg2(
    const int* __restrict__ row_ptr, const int* __restrict__ srcp,
    const float* __restrict__ eadat, const int* __restrict__ perm, int indirect,
    const float* __restrict__ We, const float* __restrict__ be,
    const float* __restrict__ fused, float* __restrict__ Xout, int N)
{
    const int wv = threadIdx.x >> 6, lane = threadIdx.x & 63;
    const int d = blockIdx.x * 4 + wv;
    if (d >= N) return;
    const int c = lane * 2;

    float2 w[21];
    #pragma unroll
    for (int j = 0; j < 21; ++j)
        w[j] = *(const float2*)(We + j * DD + c);
    const float2 b2 = *(const float2*)(be + c);
    const float2 kd = *(const float2*)(fused + (size_t)d * 512 + c);
    const float2 sk = *(const float2*)(fused + (size_t)d * 512 + 384 + c);

    float ax = 0.f, ay = 0.f;
    const int i0 = row_ptr[d], i1 = row_ptr[d + 1];
    for (int i = i0; i < i1; i += 4) {
        int idx[4];
        float2 q[4], v[4];
        #pragma unroll
        for (int t = 0; t < 4; ++t) {
            int ii = i + t; if (ii >= i1) ii = i1 - 1;
            idx[t] = srcp[ii];
        }
        #pragma unroll
        for (int t = 0; t < 4; ++t) {
            const float* fp = fused + (size_t)idx[t] * 512;
            q[t] = *(const float2*)(fp + 128 + c);
            v[t] = *(const float2*)(fp + 256 + c);
        }
        #pragma unroll
        for (int t = 0; t < 4; ++t) {
            if (i + t >= i1) break;   // wave-uniform
            const float* eap = indirect ? (eadat + (size_t)perm[i + t] * 21)
                                        : (eadat + (size_t)(i + t) * 21);
            float ex = b2.x, ey = b2.y;
            #pragma unroll
            for (int j = 0; j < 21; ++j) {
                float a = eap[j];
                ex = fmaf(a, w[j].x, ex);
                ey = fmaf(a, w[j].y, ey);
            }
            float zx = kd.x + q[t].x + ex;
            float zy = kd.y + q[t].y + ey;
            float gx = 1.f / (1.f + __expf(-zx));
            float gy = 1.f / (1.f + __expf(-zy));
            ax = fmaf(gx, v[t].x, ax);
            ay = fmaf(gy, v[t].y, ay);
        }
    }
    float2 o;
    o.x = fmaxf(ax + sk.x, 0.f);
    o.y = fmaxf(ay + sk.y, 0.f);
    *(float2*)(Xout + (size_t)d * DD + c) = o;
}

// column sums of x[N][128] into gsum[128] (gsum pre-zeroed)
__global__ void colsum_kernel(const float* __restrict__ x, float* __restrict__ gsum, int N)
{
    const int c = threadIdx.x;
    float acc = 0.f;
    for (int r = blockIdx.x; r < N; r += gridDim.x)
        acc += x[(size_t)r * DD + c];
    atomicAdd(&gsum[c], acc);
}

__global__ void cvec_kernel(const float* __restrict__ gsum, const float* __restrict__ h1W,
                            const float* __restrict__ h1b, float* __restrict__ cvec, float invN)
{
    const int m = threadIdx.x;
    float acc = h1b[m];
    for (int k = 0; k < 128; ++k)
        acc = fmaf(gsum[k] * invN, h1W[(size_t)(128 + k) * DD + m], acc);
    cvec[m] = acc;
}

__global__ __launch_bounds__(256) void head3_kernel(
    const float* __restrict__ x, const float* __restrict__ w,
    const float* __restrict__ b, float* __restrict__ out, int N)
{
    const int wave = threadIdx.x >> 6;
    const int lane = threadIdx.x & 63;
    const long n = (long)blockIdx.x * 4 + wave;
    if (n >= N) return;
    float acc = x[n * DD + lane] * w[lane] + x[n * DD + 64 + lane] * w[64 + lane];
    #pragma unroll
    for (int off = 32; off > 0; off >>= 1)
        acc += __shfl_down(acc, off, 64);
    if (lane == 0) out[n] = acc + b[0];
}

extern "C" void kernel_launch(void* const* d_in, const int* in_sizes, int n_in,
                              void* d_out, int out_size, void* d_ws, size_t ws_size,
                              hipStream_t stream)
{
    const float* G    = (const float*)d_in[0];
    const int*   ei   = (const int*)  d_in[1];
    const float* ea   = (const float*)d_in[2];
    const float* embW = (const float*)d_in[3];
    const float* embb = (const float*)d_in[4];
    const float* keyW = (const float*)d_in[5];
    const float* keyb = (const float*)d_in[6];
    const float* qryW = (const float*)d_in[7];
    const float* qryb = (const float*)d_in[8];
    const float* valW = (const float*)d_in[9];
    const float* valb = (const float*)d_in[10];
    const float* skpW = (const float*)d_in[11];
    const float* skpb = (const float*)d_in[12];
    const float* edgW = (const float*)d_in[13];
    const float* edgb = (const float*)d_in[14];
    const float* g1W  = (const float*)d_in[15];
    const float* g1b  = (const float*)d_in[16];
    const float* g2W  = (const float*)d_in[17];
    const float* g2b  = (const float*)d_in[18];
    const float* h1W  = (const float*)d_in[19];
    const float* h1b  = (const float*)d_in[20];
    const float* h2W  = (const float*)d_in[21];
    const float* h2b  = (const float*)d_in[22];
    const float* h3W  = (const float*)d_in[23];
    const float* h3b  = (const float*)d_in[24];

    const int N = in_sizes[0] / DD;    // 100000
    const int E = in_sizes[2] / 21;    // 1000000
    const int* srcA = ei;
    const int* dstA = ei + E;

    const size_t S = (size_t)N * DD;
    float* bx     = (float*)d_ws;      // [N][128]
    float* b2     = bx + S;            // [N][128]
    float* bfused = b2 + S;            // [N][512]
    float* gsum   = bfused + (size_t)N * 512;   // 128
    float* cvec   = gsum + DD;         // 128
    float* biasCat= cvec + DD;         // 1024
    unsigned short* Wt = (unsigned short*)(biasCat + 1024);  // 15*32768 ushorts
    int* hist = (int*)((char*)Wt + (size_t)15 * 32768 * 2);  // N
    int* row  = hist + N;              // N+1
    int* cur  = row + N + 1;           // N
    int* bsum = cur + N;               // 128
    int* perm = bsum + 128;            // E
    int* srcp = perm + E;              // E
    float* ea_perm = (float*)(srcp + E);   // E*21 (guarded)

    const size_t base_bytes = (size_t)((char*)ea_perm - (char*)d_ws);
    const bool room = ws_size >= base_bytes + (size_t)E * 21 * sizeof(float);

    const dim3 g1grid((N + 127) / 128, 1);
    const dim3 g4grid((N + 127) / 128, 4);
    const int aggGrid  = (N + 3) / 4;
    const int waveGrid = (N + 3) / 4;
    const int nScan = N + 1;
    const int nb = (nScan + 1023) / 1024;

    // ---- weight prep + CSR build ----
    prep_weights<<<15, 256, 0, stream>>>(embW, keyW, qryW, valW, skpW,
                                         g1W, g2W, h1W, h2W,
                                         keyb, qryb, valb, skpb, Wt, biasCat);
    hipMemsetAsync(hist, 0, (size_t)N * sizeof(int), stream);
    hist_kernel<<<1024, 256, 0, stream>>>(dstA, hist, E);
    scan1_kernel<<<nb, 256, 0, stream>>>(hist, N, row, bsum, nScan);
    scan2_kernel<<<1, 64, 0, stream>>>(bsum, nb);
    scan3_kernel<<<nb, 256, 0, stream>>>(row, bsum, cur, nScan, N);
    scatter_kernel<<<1024, 256, 0, stream>>>(srcA, dstA, cur, perm, srcp, E);
    if (room)
        permute_ea_kernel<<<2048, 256, 0, stream>>>(ea, perm, ea_perm, (long)E);
    const float* eadat = room ? ea_perm : ea;
    const int indirect = room ? 0 : 1;

    // Wt unit indices: 0-2 emb, 3-6 kqvs L0, 7-10 kqvs L1, 11 g1, 12 g2, 13 h1a, 14 h2
    #define UNIT(u) (Wt + (size_t)(u) * 32768)

    // ---- embedding MLP: G -> bx -> b2 -> bx ----
    gemm_mfma<<<g1grid, 256, 0, stream>>>(G,  UNIT(0), embb + 0,   bx, N, DD, 1);
    gemm_mfma<<<g1grid, 256, 0, stream>>>(bx, UNIT(1), embb + DD,  b2, N, DD, 1);
    gemm_mfma<<<g1grid, 256, 0, stream>>>(b2, UNIT(2), embb + 2*DD, bx, N, DD, 1);

    // ---- conv layer 0: fused kqvs -> bfused ; edges -> b2 ----
    gemm_mfma<<<g4grid, 256, 0, stream>>>(bx, UNIT(3), biasCat, bfused, N, 512, 0);
    edge_agg2<<<aggGrid, 256, 0, stream>>>(row, srcp, eadat, perm, indirect,
                                           edgW + 0, edgb + 0, bfused, b2, N);

    // ---- conv layer 1 ----
    gemm_mfma<<<g4grid, 256, 0, stream>>>(b2, UNIT(7), biasCat + 512, bfused, N, 512, 0);
    edge_agg2<<<aggGrid, 256, 0, stream>>>(row, srcp, eadat, perm, indirect,
                                           edgW + 21*DD, edgb + DD, bfused, bx, N);

    // ---- graph linears: bx -> b2 (relu) -> bx ----
    gemm_mfma<<<g1grid, 256, 0, stream>>>(bx, UNIT(11), g1b, b2, N, DD, 1);
    gemm_mfma<<<g1grid, 256, 0, stream>>>(b2, UNIT(12), g2b, bx, N, DD, 0);

    // ---- graph mean -> cvec ----
    hipMemsetAsync(gsum, 0, DD * sizeof(float), stream);
    colsum_kernel<<<256, DD, 0, stream>>>(bx, gsum, N);
    cvec_kernel<<<1, DD, 0, stream>>>(gsum, h1W, h1b, cvec, 1.0f / (float)N);

    // ---- head: h1 (bias=cvec, relu) -> b2 ; h2 -> bx ; h3 -> out ----
    gemm_mfma<<<g1grid, 256, 0, stream>>>(bx, UNIT(13), cvec, b2, N, DD, 1);
    gemm_mfma<<<g1grid, 256, 0, stream>>>(b2, UNIT(14), h2b, bx, N, DD, 1);
    head3_kernel<<<waveGrid, 256, 0, stream>>>(bx, h3W, h3b, (float*)d_out, N);
}